// Round 18
// baseline (59.027 us; speedup 1.0000x reference)
//
#include <hip/hip_runtime.h>
#include <stdint.h>

#define N 1024
#define DD 256
#define EPS 100.0f
#define INV_EPS 0.01f
#define LOG_MU -6.93147180559945f

__device__ __forceinline__ float waveReduceSum(float s) {
#pragma unroll
  for (int m = 1; m <= 32; m <<= 1) s += __shfl_xor(s, m);
  return s;
}

// Relaxed agent-scope 64-bit accesses (cache-bypassing, no cache maintenance).
__device__ __forceinline__ uint64_t rload64(const uint64_t* p) {
  return __hip_atomic_load(p, __ATOMIC_RELAXED, __HIP_MEMORY_SCOPE_AGENT);
}
__device__ __forceinline__ void rstore64(uint64_t* p, uint64_t x) {
  __hip_atomic_store(p, x, __ATOMIC_RELAXED, __HIP_MEMORY_SCOPE_AGENT);
}
__device__ __forceinline__ uint64_t packtag(uint32_t tag, float val) {
  return ((uint64_t)tag << 32) | (uint64_t)__float_as_uint(val);
}

// Single-word tagged poll: thread t owns slot t; write exp(val/eps) into sB.
__device__ __forceinline__ void stage1(const uint64_t* __restrict__ src,
                                       uint32_t want, float* sB, int t) {
  uint64_t d = rload64(src + t);
  while ((uint32_t)(d >> 32) != want) {
    __builtin_amdgcn_s_sleep(1);
    d = rload64(src + t);
  }
  sB[t] = expf(__uint_as_float((uint32_t)d) * INV_EPS);
}

#define NTAGS 6160  // U(2048) V(2048) DERR(1024) PART(1024) DONE(16)

typedef __attribute__((address_space(3))) uint32_t lds_u32_t;
typedef __attribute__((address_space(1))) const uint32_t glb_u32_t;
__device__ __forceinline__ void gload_lds16(const float* g, float* l) {
  __builtin_amdgcn_global_load_lds((glb_u32_t*)g, (lds_u32_t*)l, 16, 0, 0);
}

// ---- cmat: K=exp(-|x-y|_1/eps) and KT; zeroes tag words each call ----
// R16-proven: 64x32 tile, grid (32,16)=512 blocks (2/CU), 4x2 acc,
// global_load_lds(16) + double-buffered LDS, pre-swizzled global source.
__global__ __launch_bounds__(256) void cmat_kernel(
    const float* __restrict__ x, const float* __restrict__ y,
    float* __restrict__ Km, float* __restrict__ KTm,
    uint64_t* __restrict__ tags) {
  __shared__ float xsA[64 * 64], xsB[64 * 64];  // 16 KB each
  __shared__ float ysA[32 * 64], ysB[32 * 64];  // 8 KB each
  const int t = threadIdx.x;
  const int bj = blockIdx.x;  // 32-col tile
  const int bi = blockIdx.y;  // 64-row tile
  if (bi == 0 && bj == 0) {   // coop runs strictly after in stream order
    for (int z = t; z < NTAGS; z += 256) tags[z] = 0;
  }
  const int tx = t & 15;
  const int ty = t >> 4;
  const int c0 = tx * 2, c1 = c0 + 1;
  const int xsw = (ty & 7) << 2;         // read swizzle: ((ty*4+r)>>2)&7 = ty
  const int ysw = ((tx >> 1) & 7) << 2;  // ((2tx)>>2)&7 == ((2tx+1)>>2)&7
  const float* xg = x + (size_t)(bi * 64) * DD;
  const float* yg = y + (size_t)(bj * 32) * DD;

  float acc[4][2] = {};

  auto issue = [&](float* xs, float* ys, int kc) {
#pragma unroll
    for (int q = 0; q < 4; ++q) {  // xs: 1024 slots (64 rows x 16 granules)
      const int s = q * 256 + t;
      const int row = s >> 4, c16 = s & 15;
      const int g16 = c16 ^ ((row >> 2) & 7);  // pre-swizzled source granule
      gload_lds16(xg + (size_t)row * DD + kc + g16 * 4, xs + s * 4);
    }
#pragma unroll
    for (int q = 0; q < 2; ++q) {  // ys: 512 slots (32 rows x 16 granules)
      const int s = q * 256 + t;
      const int row = s >> 4, c16 = s & 15;
      const int g16 = c16 ^ ((row >> 2) & 7);
      gload_lds16(yg + (size_t)row * DD + kc + g16 * 4, ys + s * 4);
    }
  };

  auto compute = [&](const float* xs, const float* ys) {
#pragma unroll 2
    for (int kk = 0; kk < 64; kk += 4) {
      float4 xr[4];
#pragma unroll
      for (int r = 0; r < 4; ++r)
        xr[r] = *reinterpret_cast<const float4*>(
            &xs[(ty * 4 + r) * 64 + (kk ^ xsw)]);
      const float4 ya =
          *reinterpret_cast<const float4*>(&ys[c0 * 64 + (kk ^ ysw)]);
      const float4 yb =
          *reinterpret_cast<const float4*>(&ys[c1 * 64 + (kk ^ ysw)]);
#pragma unroll
      for (int r = 0; r < 4; ++r) {
        acc[r][0] += fabsf(xr[r].x - ya.x) + fabsf(xr[r].y - ya.y) +
                     fabsf(xr[r].z - ya.z) + fabsf(xr[r].w - ya.w);
        acc[r][1] += fabsf(xr[r].x - yb.x) + fabsf(xr[r].y - yb.y) +
                     fabsf(xr[r].z - yb.z) + fabsf(xr[r].w - yb.w);
      }
    }
  };

  issue(xsA, ysA, 0);
  __syncthreads();  // vmcnt drained by barrier -> chunk 0 resident
  issue(xsB, ysB, 64);
  compute(xsA, ysA);
  __syncthreads();  // all reads of A done; B's loads drained
  issue(xsA, ysA, 128);
  compute(xsB, ysB);
  __syncthreads();
  issue(xsB, ysB, 192);
  compute(xsA, ysA);
  __syncthreads();
  compute(xsB, ysB);

  float kv[4][2];
#pragma unroll
  for (int r = 0; r < 4; ++r) {
    kv[r][0] = expf(-acc[r][0] * INV_EPS);
    kv[r][1] = expf(-acc[r][1] * INV_EPS);
  }
  const int gr0 = bi * 64 + ty * 4;
  const int gc0 = bj * 32 + c0;
#pragma unroll
  for (int r = 0; r < 4; ++r)
    *reinterpret_cast<float2*>(Km + (size_t)(gr0 + r) * N + gc0) =
        make_float2(kv[r][0], kv[r][1]);
  // KT via LDS transpose (reuse xsA = trans[32][64], XOR-swizzled granules).
  float* trans = xsA;
  const int tsw = (tx >> 1) & 7;  // (c0>>2)&7 == (c1>>2)&7
#pragma unroll
  for (int r = 0; r < 4; ++r) {
    trans[c0 * 64 + ((ty ^ tsw) << 2) + r] = kv[r][0];
    trans[c1 * 64 + ((ty ^ tsw) << 2) + r] = kv[r][1];
  }
  __syncthreads();
#pragma unroll
  for (int it = 0; it < 2; ++it) {
    const int l = it * 256 + t;
    const int crow = l >> 4, cq = l & 15;  // crow: col of K (row of KT)
    const float4 val = *reinterpret_cast<const float4*>(
        &trans[crow * 64 + ((cq ^ ((crow >> 2) & 7)) << 2)]);
    *reinterpret_cast<float4*>(KTm + (size_t)(bj * 32 + crow) * N + bi * 64 +
                               cq * 4) = val;
  }
}

// ---- persistent Sinkhorn: tagged dataflow + off-path aggregator ----
// 1024-thread compute blocks: wave w handles quarter q=w>>2 of row/col
// i = b*4 + (w&3); quarters combined via 16-slot LDS partials; q==0 waves do
// the scalar update + publish. Poll depth = 1 tagged word per thread.
// Hop structure, tags, aggregator, fused loss, early-exit unchanged.
__global__ __launch_bounds__(1024, 1) void sinkhorn_coop(
    const float* __restrict__ Km, const float* __restrict__ KTm,
    uint64_t* __restrict__ U, uint64_t* __restrict__ V,
    uint64_t* __restrict__ DERR, uint64_t* __restrict__ PART,
    uint64_t* __restrict__ DONE, float* __restrict__ out) {
  const int b = blockIdx.x, t = threadIdx.x;
  const int lane = t & 63, w = t >> 6;

  if (b == 256) {  // ---- aggregator block (wave 0 only) ----
    if (w != 0) return;
    for (int it = 0; it < 9; ++it) {
      const uint32_t k = it + 1;
      float e = 0.f;
#pragma unroll
      for (int q = 0; q < 16; ++q) {
        const int idx = q * 64 + lane;
        uint64_t d;
        while ((uint32_t)((d = rload64(DERR + idx)) >> 32) != k)
          __builtin_amdgcn_s_sleep(1);
        e += __uint_as_float((uint32_t)d);
      }
      e = waveReduceSum(e);
      if (lane == 0)
        rstore64(DONE + it, ((uint64_t)k << 32) | (e < 0.1f ? 1u : 0u));
      if (__shfl(e, 0) < 0.1f) return;  // later DERR tags never arrive
    }
    return;
  }

  __shared__ float sB[N];
  __shared__ float sPart[16];
  __shared__ float sPart2[16];
  __shared__ float sRed[16];
  __shared__ int sDone;
  const int rw = w & 3;    // which of the block's 4 rows/cols
  const int qt = w >> 2;   // which 256-element quarter of the matvec
  const int i = b * 4 + rw;
  const float* Krow = Km + (size_t)i * N;
  const float* Trow = KTm + (size_t)i * N;

  float ui = 0.f, vj = 0.f;  // tracked by qt==0 waves
  int klast = 0;

  for (int it = 0; it < 10; ++it) {
    const uint32_t k = it + 1;
    // ---- stage b_j = exp(v^{k-1}_j/eps); k-1==0 -> ones ----
    if (it == 0) {
      sB[t] = 1.0f;
    } else {
      stage1(V + (size_t)((k - 1) & 1) * N, k - 1, sB, t);
    }
    __syncthreads();
    // ---- row pass (quarter-matvec per wave) ----
    {
      const int j4 = qt * 256 + lane * 4;
      const float4 k4 = *reinterpret_cast<const float4*>(Krow + j4);
      const float4 b4 = *reinterpret_cast<const float4*>(&sB[j4]);
      float s = k4.x * b4.x + k4.y * b4.y + k4.z * b4.z + k4.w * b4.w;
      s = waveReduceSum(s);
      if (lane == 0) sPart[w] = s;
    }
    __syncthreads();  // partials ready; also: all sB reads done
    if (qt == 0) {
      const float s = sPart[rw] + sPart[rw + 4] + sPart[rw + 8] + sPart[rw + 12];
      const float un =
          EPS * (LOG_MU - logf(expf(ui * INV_EPS) * s + 1e-6f)) + ui;
      const float de = fabsf(un - ui);
      ui = un;
      if (lane == 0) {
        rstore64(U + (size_t)(k & 1) * N + i, packtag(k, ui));
        if (it < 9) rstore64(DERR + i, packtag(k, de));
      }
    }
    // ---- stage a_i = exp(u^k_i/eps) (tag-synchronized, no barrier) ----
    stage1(U + (size_t)(k & 1) * N, k, sB, t);
    __syncthreads();
    // ---- col pass (quarter-matvec per wave); iteration 10 fuses loss ----
    if (it < 9) {
      const int i4 = qt * 256 + lane * 4;
      const float4 k4 = *reinterpret_cast<const float4*>(Trow + i4);
      const float4 a4 = *reinterpret_cast<const float4*>(&sB[i4]);
      float s = k4.x * a4.x + k4.y * a4.y + k4.z * a4.z + k4.w * a4.w;
      s = waveReduceSum(s);
      if (lane == 0) sPart[w] = s;
      __syncthreads();
      if (qt == 0) {
        const float s2 =
            sPart[rw] + sPart[rw + 4] + sPart[rw + 8] + sPart[rw + 12];
        vj = EPS * (LOG_MU - logf(expf(vj * INV_EPS) * s2 + 1e-6f)) + vj;
        if (lane == 0) rstore64(V + (size_t)(k & 1) * N + i, packtag(k, vj));
      }
      klast = (int)k;
      // ---- DONE poll (aggregator published it during our col pass) ----
      if (t == 0) {
        uint64_t d;
        while ((uint32_t)((d = rload64(DONE + it)) >> 32) != k)
          __builtin_amdgcn_s_sleep(1);
        sDone = (int)(d & 1);
      }
      __syncthreads();  // also guards sB restage of next iteration
      if (sDone) break;
    } else {
      // last col pass: s = sum KT*a ; sl = sum KT*a*C, C = -eps*ln(KT)
      const int i4 = qt * 256 + lane * 4;
      const float4 k4 = *reinterpret_cast<const float4*>(Trow + i4);
      const float4 a4 = *reinterpret_cast<const float4*>(&sB[i4]);
      const float p0 = k4.x * a4.x, p1 = k4.y * a4.y, p2 = k4.z * a4.z,
                  p3 = k4.w * a4.w;
      float s = p0 + p1 + p2 + p3;
      float sl = p0 * logf(k4.x) + p1 * logf(k4.y) + p2 * logf(k4.z) +
                 p3 * logf(k4.w);
      s = waveReduceSum(s);
      sl = waveReduceSum(sl);
      if (lane == 0) {
        sPart[w] = s;
        sPart2[w] = sl;
      }
      __syncthreads();
      if (qt == 0) {
        const float s2 =
            sPart[rw] + sPart[rw + 4] + sPart[rw + 8] + sPart[rw + 12];
        const float sl2 =
            (sPart2[rw] + sPart2[rw + 4] + sPart2[rw + 8] + sPart2[rw + 12]) *
            -EPS;
        vj = EPS * (LOG_MU - logf(expf(vj * INV_EPS) * s2 + 1e-6f)) + vj;
        if (lane == 0)
          rstore64(PART + i, packtag(1u, expf(vj * INV_EPS) * sl2));
      }
      klast = 10;
    }
  }
  __syncthreads();  // iteration partial reads done before sRed reuse below
  // ---- early-exit loss path (statically unreachable for this input) ----
  if (klast < 10) {
    stage1(V + (size_t)(klast & 1) * N, (uint32_t)klast, sB, t);
    __syncthreads();
    if (qt == 0) {
      float sl = 0.f;
#pragma unroll
      for (int q = 0; q < 4; ++q) {
        const int j4 = (q * 64 + lane) * 4;
        const float4 k4 = *reinterpret_cast<const float4*>(Krow + j4);
        sl += (k4.x * sB[j4]) * logf(k4.x) +
              (k4.y * sB[j4 + 1]) * logf(k4.y) +
              (k4.z * sB[j4 + 2]) * logf(k4.z) +
              (k4.w * sB[j4 + 3]) * logf(k4.w);
      }
      sl = waveReduceSum(sl) * -EPS;
      if (lane == 0) rstore64(PART + i, packtag(1u, expf(ui * INV_EPS) * sl));
    }
  }
  // ---- final reduce: block 0 polls 1024 partials (1 per thread) ----
  if (b == 0) {
    uint64_t d = rload64(PART + t);
    while ((uint32_t)(d >> 32) != 1u) {
      __builtin_amdgcn_s_sleep(1);
      d = rload64(PART + t);
    }
    float acc = __uint_as_float((uint32_t)d);
    acc = waveReduceSum(acc);
    if (lane == 0) sRed[w] = acc;
    __syncthreads();
    if (t == 0) {
      float a = 0.f;
#pragma unroll
      for (int q = 0; q < 16; ++q) a += sRed[q];
      out[0] = a;
    }
  }
}

extern "C" void kernel_launch(void* const* d_in, const int* in_sizes, int n_in,
                              void* d_out, int out_size, void* d_ws,
                              size_t ws_size, hipStream_t stream) {
  const float* x = (const float*)d_in[0];  // "output"
  const float* y = (const float*)d_in[1];  // "target"
  float* out = (float*)d_out;

  const size_t nn = (size_t)N * N;
  float* Km = (float*)d_ws;
  float* KTm = Km + nn;
  uint64_t* tags = (uint64_t*)(KTm + nn);
  uint64_t* U = tags;          // 2*N
  uint64_t* V = U + 2 * N;     // 2*N
  uint64_t* DERR = V + 2 * N;  // N
  uint64_t* PART = DERR + N;   // N
  uint64_t* DONE = PART + N;   // 16

  cmat_kernel<<<dim3(32, 16), 256, 0, stream>>>(x, y, Km, KTm, tags);
  sinkhorn_coop<<<257, 1024, 0, stream>>>(Km, KTm, U, V, DERR, PART, DONE,
                                          out);
}